// Round 15
// baseline (55.216 us; speedup 1.0000x reference)
//
#include <hip/hip_runtime.h>
#include <math.h>

#define N_NODES 100000
#define N_EDGES 1000000
#define NPAIR 32
#define CUTOFF 6.0f

#define CHUNK 512
#define NCHUNK 196                                // ceil(100000/512)
#define CAP 8192                                  // padded mean ~7000, ~15 sigma margin
#define K1_THREADS 1024
#define EPT 4
#define EPB (K1_THREADS * EPT)                    // 4096
#define K1_BLOCKS ((N_EDGES + EPB - 1) / EPB)     // 245
#define CURSTRIDE 16
#define NCUR (NCHUNK * CURSTRIDE)                 // 3136

#define HALF 256                                  // nodes per accum block
#define NB_ACC (NCHUNK * 2)                       // 392
#define NODECAP 32                                // per-node LDS bin capacity (lambda 9.3 -> ~+7 sigma)
#define BSTRIDE 33                                // padded stride: bank-conflict-free readback

// workspace: bucket 6,422,528 + cur 12,544 + packed 1,600,000 = 8,035,072 B (< 12.27 MB proven bound)

// ---------------- pass 0: pack pos+z+batch into one float4; zero cursors ----------------
__global__ __launch_bounds__(256) void pack_kernel(
    const float* __restrict__ pos,    // [N,3]
    const int*   __restrict__ z,      // [N]
    const int*   __restrict__ batch,  // [N]
    float4*      __restrict__ packed, // [N]
    int*         __restrict__ cur)    // [NCUR]
{
    int n = blockIdx.x * 256 + threadIdx.x;
    if (n < NCUR) cur[n] = 0;
    if (n < N_NODES) {
        float4 p;
        p.x = pos[3 * n + 0];
        p.y = pos[3 * n + 1];
        p.z = pos[3 * n + 2];
        p.w = __int_as_float((z[n] & 3) | (batch[n] << 2));
        packed[n] = p;
    }
}

// ---------------- pass 1 (R7-proven, ~13-15us): float4 gathers, cursor line-aligned runs ----------------
__global__ __launch_bounds__(1024) void bin_kernel(
    const float4* __restrict__ packed,    // [N] {x,y,z, bits}
    const float*  __restrict__ cell,      // [G,3,3]
    const float*  __restrict__ shift,     // [E,3]
    const int*    __restrict__ ei,        // [2,E]
    unsigned int* __restrict__ bucket,    // [NCHUNK][CAP]
    int*          __restrict__ cur)       // [NCUR] line-padded cursors (zeroed by pack)
{
    __shared__ int lhist[NCHUNK];
    __shared__ int lbase[NCHUNK];
    int tid = threadIdx.x;

    if (tid < NCHUNK) lhist[tid] = 0;
    __syncthreads();

    int base = blockIdx.x * EPB;

    // phase 1: coalesced edge loads
    int iv[EPT], jv[EPT];
    float sx[EPT], sy[EPT], sz[EPT];
    bool val[EPT];
#pragma unroll
    for (int q = 0; q < EPT; ++q) {
        int e = base + tid + q * K1_THREADS;
        val[q] = (e < N_EDGES);
        int ee = val[q] ? e : 0;
        iv[q] = ei[ee];
        jv[q] = ei[N_EDGES + ee];
        sx[q] = shift[3 * ee + 0];
        sy[q] = shift[3 * ee + 1];
        sz[q] = shift[3 * ee + 2];
    }

    // phase 2: 2 dwordx4 gathers per edge
    float4 fi[EPT], fj[EPT];
#pragma unroll
    for (int q = 0; q < EPT; ++q) {
        fi[q] = packed[iv[q]];
        fj[q] = packed[jv[q]];
    }

    // phase 3: compute r, pack record, local histogram
    unsigned int recs[EPT];
    int chks[EPT], locs[EPT];
#pragma unroll
    for (int q = 0; q < EPT; ++q) {
        chks[q] = -1;
        if (val[q]) {
            int bi = __float_as_int(fi[q].w) >> 2;
            int zj = __float_as_int(fj[q].w) & 3;
            const float* C = cell + 9 * bi;
            float vx = fj[q].x - fi[q].x + sx[q] * C[0] + sy[q] * C[3] + sz[q] * C[6];
            float vy = fj[q].y - fi[q].y + sx[q] * C[1] + sy[q] * C[4] + sz[q] * C[7];
            float vz = fj[q].z - fi[q].z + sx[q] * C[2] + sy[q] * C[5] + sz[q] * C[8];
            float r = sqrtf(vx * vx + vy * vy + vz * vz);
            if (r < CUTOFF) {
                unsigned int qq = (unsigned int)(r * (2097152.0f / 6.0f));
                qq = min(qq, 2097151u);
                int c = iv[q] >> 9;                     // chunk (512 nodes)
                recs[q] = (qq << 11) | ((unsigned int)(iv[q] & 511) << 2)
                        | (unsigned int)zj;             // spec 0..2 (3 = sentinel)
                chks[q] = c;
                locs[q] = atomicAdd(&lhist[c], 1);
            }
        }
    }
    __syncthreads();

    // one line-aligned global reservation per touched (block, chunk)
    if (tid < NCHUNK) {
        int h  = lhist[tid];
        int hp = (h + 15) & ~15;                        // round up to 64B line
        lbase[tid] = (hp > 0) ? atomicAdd(&cur[tid * CURSTRIDE], hp) : 0;
    }
    __syncthreads();

    // scatter records (run-contiguous; every line owned by this block)
#pragma unroll
    for (int q = 0; q < EPT; ++q) {
        if (chks[q] >= 0) {
            int slot = lbase[chks[q]] + locs[q];
            if (slot < CAP)
                bucket[(size_t)chks[q] * CAP + slot] = recs[q];
        }
    }

    // sentinel-fill the pad slots
    if (tid < NCHUNK) {
        int h  = lhist[tid];
        int hp = (h + 15) & ~15;
        int b  = lbase[tid];
        for (int k = h; k < hp; ++k) {
            int slot = b + k;
            if (slot < CAP)
                bucket[(size_t)tid * CAP + slot] = 0xFFFFFFFFu;
        }
    }
}

// ---------------- pass 2: sort-free direct scatter into per-node LDS bins + register accumulation ----------------
__global__ __launch_bounds__(256, 1) void accum_kernel(
    const unsigned int* __restrict__ bucket,  // [NCHUNK][CAP]
    const int*          __restrict__ cur,     // padded counts (multiples of 16)
    float*              __restrict__ out)     // [96, N]
{
    __shared__ unsigned int bins[HALF * BSTRIDE];  // 33.8 KB
    __shared__ int lcur[HALF];
    int tid = threadIdx.x;
    int chunk = blockIdx.x >> 1;
    int half  = blockIdx.x & 1;
    int locbase = half * HALF;

    lcur[tid] = 0;
    __syncthreads();

    int cnt = min(cur[chunk * CURSTRIDE], CAP);    // multiple of 16 -> uint4-exact
    const uint4* b4 = (const uint4*)(bucket + (size_t)chunk * CAP);
    int n4 = cnt >> 2;

    // single pass: sentinel-skip + half-filter + one LDS atomic per kept record
    for (int k = tid; k < n4; k += 256) {
        uint4 v = b4[k];
        unsigned int rr[4] = {v.x, v.y, v.z, v.w};
#pragma unroll
        for (int u = 0; u < 4; ++u) {
            unsigned int rc = rr[u];
            if ((rc & 3u) != 3u) {
                int l = (int)((rc >> 2) & 511) - locbase;
                if ((unsigned)l < HALF) {
                    int slot = atomicAdd(&lcur[l], 1);
                    if (slot < NODECAP) bins[l * BSTRIDE + slot] = rc;
                }
            }
        }
    }
    __syncthreads();

    // register accumulation: thread t owns node chunk*512 + locbase + t
    int n = min(lcur[tid], NODECAP);
    float a0[NPAIR], a1[NPAIR], a2[NPAIR];
#pragma unroll
    for (int p = 0; p < NPAIR; ++p) { a0[p] = 0.0f; a1[p] = 0.0f; a2[p] = 0.0f; }

    for (int k = 0; k < n; ++k) {
        unsigned int rc = bins[tid * BSTRIDE + k];
        int spec = rc & 3;
        float r = (float)(rc >> 11) * (6.0f / 2097152.0f);
        float fc = 0.5f * (__cosf(r * (float)(M_PI / 6.0)) + 1.0f);
        float m0 = (spec == 0) ? fc : 0.0f;
        float m1 = (spec == 1) ? fc : 0.0f;
        float m2 = (spec == 2) ? fc : 0.0f;
        // etas = {0.5,1,2,4}/36: one exp, repeated squaring
#pragma unroll
        for (int o = 0; o < 8; ++o) {
            float d = r - (float)o;
            float e0 = __expf(d * d * (-0.5f / 36.0f));
            float e1 = e0 * e0;
            float e2 = e1 * e1;
            float e3 = e2 * e2;
            a0[o]      = fmaf(m0, e0, a0[o]);
            a1[o]      = fmaf(m1, e0, a1[o]);
            a2[o]      = fmaf(m2, e0, a2[o]);
            a0[8 + o]  = fmaf(m0, e1, a0[8 + o]);
            a1[8 + o]  = fmaf(m1, e1, a1[8 + o]);
            a2[8 + o]  = fmaf(m2, e1, a2[8 + o]);
            a0[16 + o] = fmaf(m0, e2, a0[16 + o]);
            a1[16 + o] = fmaf(m1, e2, a1[16 + o]);
            a2[16 + o] = fmaf(m2, e2, a2[16 + o]);
            a0[24 + o] = fmaf(m0, e3, a0[24 + o]);
            a1[24 + o] = fmaf(m1, e3, a1[24 + o]);
            a2[24 + o] = fmaf(m2, e3, a2[24 + o]);
        }
    }

    int node = chunk * CHUNK + locbase + tid;
    if (node < N_NODES) {
#pragma unroll
        for (int p = 0; p < NPAIR; ++p) {
            out[(size_t)(0 * NPAIR + p) * N_NODES + node] = a0[p];
            out[(size_t)(1 * NPAIR + p) * N_NODES + node] = a1[p];
            out[(size_t)(2 * NPAIR + p) * N_NODES + node] = a2[p];
        }
    }
}

extern "C" void kernel_launch(void* const* d_in, const int* in_sizes, int n_in,
                              void* d_out, int out_size, void* d_ws, size_t ws_size,
                              hipStream_t stream) {
    const float* pos   = (const float*)d_in[0];
    const float* cell  = (const float*)d_in[1];
    const float* shift = (const float*)d_in[2];
    const int*   z     = (const int*)d_in[5];
    const int*   ei    = (const int*)d_in[6];
    const int*   batch = (const int*)d_in[7];
    float* out = (float*)d_out;

    char* ws = (char*)d_ws;
    unsigned int* bucket = (unsigned int*)ws;          // 6,422,528 B
    int*          cur    = (int*)(ws + 6422528);       // 12,544 B
    float4*       packed = (float4*)(ws + 6435072);    // 1,600,000 B -> total 8,035,072 B

    int pblocks = (N_NODES + 255) / 256;               // 391 (covers NCUR zeroing)
    pack_kernel<<<pblocks, 256, 0, stream>>>(pos, z, batch, packed, cur);
    bin_kernel<<<K1_BLOCKS, K1_THREADS, 0, stream>>>(packed, cell, shift, ei, bucket, cur);
    accum_kernel<<<NB_ACC, 256, 0, stream>>>(bucket, cur, out);
}